// Round 6
// baseline (139.953 us; speedup 1.0000x reference)
//
#include <hip/hip_runtime.h>
#include <math.h>

#define N_ 64
#define L_ 256
#define D_ 1024
#define M_ 128
#define BK 64

typedef float f4 __attribute__((ext_vector_type(4)));
typedef short bf16x8 __attribute__((ext_vector_type(8)));
typedef short s8v __attribute__((ext_vector_type(8)));
typedef float f32x4 __attribute__((ext_vector_type(4)));
typedef int i4 __attribute__((ext_vector_type(4)));

// ---------------- fp32 -> bf16 (RNE) + row sum-of-squares (x and y fused) ----------------
__global__ __launch_bounds__(256) void convert_ssq_kernel(const float* __restrict__ x,
                                                          const float* __restrict__ y,
                                                          short* __restrict__ xh,
                                                          short* __restrict__ yh,
                                                          float* __restrict__ sqx,
                                                          float* __restrict__ sqy) {
    int w = threadIdx.x >> 6, lane = threadIdx.x & 63;
    int row = blockIdx.x * 4 + w;
    const float* in;
    short* hi;
    float* ssq;
    int r;
    if (row < N_ * L_) { in = x; hi = xh; ssq = sqx; r = row; }
    else               { in = y; hi = yh; ssq = sqy; r = row - N_ * L_; }
    const f4* p = (const f4*)(in + (size_t)r * D_);
    float s = 0.f;
#pragma unroll
    for (int rep = 0; rep < 2; ++rep) {
        f4 v0 = p[rep * 128 + lane * 2];
        f4 v1 = p[rep * 128 + lane * 2 + 1];
        s8v h;
#pragma unroll
        for (int j = 0; j < 4; ++j) {
            float f = v0[j]; s = fmaf(f, f, s);
            unsigned u = __float_as_uint(f);
            h[j] = (short)((u + 0x7FFFu + ((u >> 16) & 1u)) >> 16);
        }
#pragma unroll
        for (int j = 0; j < 4; ++j) {
            float f = v1[j]; s = fmaf(f, f, s);
            unsigned u = __float_as_uint(f);
            h[4 + j] = (short)((u + 0x7FFFu + ((u >> 16) & 1u)) >> 16);
        }
        *(s8v*)(hi + (size_t)r * D_ + rep * 512 + lane * 8) = h;
    }
#pragma unroll
    for (int off = 32; off; off >>= 1) s += __shfl_down(s, off);
    if (lane == 0) ssq[r] = s;
}

// LDS tile layout: row stride 128B (64 bf16), 8 slots of 16B, slot XOR-swizzled by row
__device__ __forceinline__ int swz(int row, int slot) {
    return (row << 7) + (((slot) ^ (row & 7)) << 4);
}

// exactly 6 global_load_lds per thread (per wave) -- vmcnt counting depends on this
__device__ __forceinline__ void stage_tile(const short* __restrict__ A,
                                           const short* __restrict__ B,
                                           char* lds, int abase, int bbase,
                                           int k0, int tid) {
    int wofs = (tid >> 6) << 10;
    int r8 = tid >> 3;
    int sl = tid & 7;
#pragma unroll
    for (int i = 0; i < 4; ++i) {
        int row = i * 32 + r8;
        int ss = sl ^ (row & 7);
        __builtin_amdgcn_global_load_lds(
            (const __attribute__((address_space(1))) void*)(A + (size_t)row * D_ + k0 + (ss << 3)),
            (__attribute__((address_space(3))) void*)(lds + abase + (i << 12) + wofs),
            16, 0, 0);
    }
#pragma unroll
    for (int i = 0; i < 2; ++i) {
        int row = i * 32 + r8;
        int ss = sl ^ (row & 7);
        __builtin_amdgcn_global_load_lds(
            (const __attribute__((address_space(1))) void*)(B + (size_t)row * D_ + k0 + (ss << 3)),
            (__attribute__((address_space(3))) void*)(lds + bbase + (i << 12) + wofs),
            16, 0, 0);
    }
}

__device__ __forceinline__ void compute_tile(const char* lds, int abase, int bbase,
                                             int wr, int wc, int fr, int kg,
                                             f32x4 acc[4][2]) {
    bf16x8 a[4][2], b[2][2];
#pragma unroll
    for (int fi = 0; fi < 4; ++fi) {
        int row = (wr << 6) + (fi << 4) + fr;
#pragma unroll
        for (int kh = 0; kh < 2; ++kh)
            a[fi][kh] = *(const bf16x8*)(lds + abase + swz(row, (kh << 2) | kg));
    }
#pragma unroll
    for (int fj = 0; fj < 2; ++fj) {
        int col = (wc << 5) + (fj << 4) + fr;
#pragma unroll
        for (int kh = 0; kh < 2; ++kh)
            b[fj][kh] = *(const bf16x8*)(lds + bbase + swz(col, (kh << 2) | kg));
    }
    __builtin_amdgcn_s_setprio(1);
#pragma unroll
    for (int kh = 0; kh < 2; ++kh)
#pragma unroll
        for (int fi = 0; fi < 4; ++fi)
#pragma unroll
            for (int fj = 0; fj < 2; ++fj)
                acc[fi][fj] = __builtin_amdgcn_mfma_f32_16x16x32_bf16(a[fi][kh], b[fj][kh], acc[fi][fj], 0, 0, 0);
    __builtin_amdgcn_s_setprio(0);
}

// ---------------- fused bf16 MFMA GEMM + sqrt/mask epilogue ----------------
// XCD-grouped mapping (block b -> XCD b&7; XCD x owns n in [8x,8x+8)): per-XCD
// working set ~4.25 MB =~ one L2 (verified: FETCH 240 MB -> 17.6 MB).
// K-loop: T4 counted-vmcnt 2-phase -- next-tile loads stay in flight across
// raw s_barriers; no vmcnt(0) drain inside the loop.
__global__ __launch_bounds__(256) void ed_mfma_kernel(
        const short* __restrict__ xh, const short* __restrict__ yh,
        const float* __restrict__ sqx, const float* __restrict__ sqy,
        const int* __restrict__ mask,
        float* __restrict__ ed_raw, float* __restrict__ edq) {
    __shared__ __align__(16) char lds[49152];  // [A0 16K][B0 8K][A1 16K][B1 8K]
    int tid = threadIdx.x;
    int b = blockIdx.x;
    int wid = tid >> 6, lane = tid & 63;
    int wr = wid >> 1, wc = wid & 1;

    int xcd = b & 7;
    int slot = b >> 3;            // 0..95
    int n = xcd * 8 + slot / 12;
    int r = slot % 12;

    int l0, c0, mode;
    const short *Ah, *Bh;
    if (r < 4) {
        mode = 0;
        l0 = (r >> 1) << 7; c0 = (r & 1) << 6;
        Bh = yh + (size_t)c0 * D_;
    } else {
        mode = 1;
        int rr = r - 4;
        l0 = (rr >> 2) << 7; c0 = (rr & 3) << 6;
        Bh = xh + ((size_t)n * L_ + c0) * D_;
    }
    Ah = xh + ((size_t)n * L_ + l0) * D_;

    f32x4 acc[4][2];
#pragma unroll
    for (int i = 0; i < 4; ++i)
#pragma unroll
        for (int j = 0; j < 2; ++j)
            acc[i][j] = (f32x4){0.f, 0.f, 0.f, 0.f};

    int fr = lane & 15, kg = lane >> 4;

    int buf = 0;
    stage_tile(Ah, Bh, lds, 0, 16384, 0, tid);     // 6 loads in flight, no drain
    for (int t = 0; t < 15; ++t) {
        int nb = buf ^ 1;
        stage_tile(Ah, Bh, lds, nb * 24576, nb * 24576 + 16384, (t + 1) * BK, tid);
        // wait for the OLDER batch (current buffer) only; 6 next-tile loads stay in flight
        asm volatile("s_waitcnt vmcnt(6)" ::: "memory");
        __builtin_amdgcn_sched_barrier(0);
        __builtin_amdgcn_s_barrier();              // all waves' current-buffer stages landed
        compute_tile(lds, buf * 24576, buf * 24576 + 16384, wr, wc, fr, kg, acc);
        __builtin_amdgcn_sched_barrier(0);
        __builtin_amdgcn_s_barrier();              // reads of buf done before it is restaged
        buf = nb;
    }
    asm volatile("s_waitcnt vmcnt(0)" ::: "memory");
    __builtin_amdgcn_sched_barrier(0);
    __builtin_amdgcn_s_barrier();
    compute_tile(lds, buf * 24576, buf * 24576 + 16384, wr, wc, fr, kg, acc);

    int rbase = (lane >> 4) << 2;

    if (mode == 0) {
        float sy[2];
#pragma unroll
        for (int fj = 0; fj < 2; ++fj)
            sy[fj] = sqy[c0 + (wc << 5) + (fj << 4) + fr];
        float colsum[2] = {0.f, 0.f};
#pragma unroll
        for (int fi = 0; fi < 4; ++fi) {
#pragma unroll
            for (int rr = 0; rr < 4; ++rr) {
                int gl = l0 + (wr << 6) + (fi << 4) + rbase + rr;
                float sx = sqx[n * L_ + gl];
                float mf = (float)mask[n * L_ + gl];
#pragma unroll
                for (int fj = 0; fj < 2; ++fj) {
                    float raw = fmaf(-2.f, acc[fi][fj][rr], sx + sy[fj]);
                    float dd = raw > 0.f ? sqrtf(raw) : 0.f;
                    colsum[fj] = fmaf(dd, mf, colsum[fj]);
                }
            }
        }
#pragma unroll
        for (int fj = 0; fj < 2; ++fj) {
            colsum[fj] += __shfl_xor(colsum[fj], 16);
            colsum[fj] += __shfl_xor(colsum[fj], 32);
        }
        if (lane < 16) {
#pragma unroll
            for (int fj = 0; fj < 2; ++fj)
                atomicAdd(&ed_raw[n * M_ + c0 + (wc << 5) + (fj << 4) + lane], colsum[fj]);
        }
    } else {
        int gj[2];
        float sj[2], mj[2];
#pragma unroll
        for (int fj = 0; fj < 2; ++fj) {
            gj[fj] = c0 + (wc << 5) + (fj << 4) + fr;
            sj[fj] = sqx[n * L_ + gj[fj]];
            mj[fj] = (float)mask[n * L_ + gj[fj]];
        }
        float tot = 0.f;
#pragma unroll
        for (int fi = 0; fi < 4; ++fi) {
#pragma unroll
            for (int rr = 0; rr < 4; ++rr) {
                int gl = l0 + (wr << 6) + (fi << 4) + rbase + rr;
                float sx = sqx[n * L_ + gl];
                float mf = (float)mask[n * L_ + gl];
#pragma unroll
                for (int fj = 0; fj < 2; ++fj) {
                    float raw = fmaf(-2.f, acc[fi][fj][rr], sx + sj[fj]);
                    float dd = raw > 0.f ? sqrtf(raw) : 0.f;
                    if (gl == gj[fj]) dd = 0.f;   // exact-zero diagonal
                    tot = fmaf(dd * mf, mj[fj], tot);
                }
            }
        }
#pragma unroll
        for (int off = 32; off; off >>= 1) tot += __shfl_xor(tot, off);
        if (lane == 0) atomicAdd(&edq[n], tot);
    }
}

// ---------------- final: mask sums + scores -> log_softmax -> loss ----------------
__global__ __launch_bounds__(256) void score_kernel(const float* __restrict__ ed_raw,
                                                    const float* __restrict__ edq,
                                                    const int* __restrict__ mask,
                                                    float* __restrict__ out) {
    __shared__ float sc[N_ * M_];   // 32 KB
    __shared__ float Ssh[N_];
    __shared__ float red[N_];
    int tid = threadIdx.x;
    {   // mask sums: thread t sums 64 consecutive ints; 4 threads per n
        const i4* mp = (const i4*)(mask + tid * 64);
        int s = 0;
#pragma unroll
        for (int i = 0; i < 16; ++i) { i4 v = mp[i]; s += v[0] + v[1] + v[2] + v[3]; }
        s += __shfl_xor(s, 1);
        s += __shfl_xor(s, 2);
        if ((tid & 3) == 0) Ssh[tid >> 2] = (float)s;
    }
    __syncthreads();
    for (int i = tid; i < N_ * M_; i += 256) {
        int n = i >> 7;
        float Sn = Ssh[n];
        float valid1 = fmaxf(Sn, 1.f);
        float edq_n = edq[n] / fmaxf(Sn * Sn, 1.f);
        sc[i] = -20.f * (2.f * ed_raw[i] / valid1 - edq_n);
    }
    __syncthreads();
    int n = tid >> 2, q = tid & 3;
    const float* row = sc + n * M_;
    float mx = -INFINITY;
    for (int m = q * 32; m < q * 32 + 32; ++m) mx = fmaxf(mx, row[m]);
    mx = fmaxf(mx, __shfl_xor(mx, 1));
    mx = fmaxf(mx, __shfl_xor(mx, 2));
    float se = 0.f;
    for (int m = q * 32; m < q * 32 + 32; ++m) se += expf(row[m] - mx);
    se += __shfl_xor(se, 1);
    se += __shfl_xor(se, 2);
    if (q == 0) red[n] = -(row[n] - mx - logf(se));
    __syncthreads();
    if (tid < 64) {
        float v = red[tid];
#pragma unroll
        for (int off = 32; off; off >>= 1) v += __shfl_down(v, off);
        if (tid == 0) out[0] = v * (1.f / (float)N_);
    }
}

extern "C" void kernel_launch(void* const* d_in, const int* in_sizes, int n_in,
                              void* d_out, int out_size, void* d_ws, size_t ws_size,
                              hipStream_t stream) {
    const float* x = (const float*)d_in[0];
    const float* y = (const float*)d_in[1];
    const int* mask = (const int*)d_in[2];

    char* base = (char*)d_ws;
    float* sqx    = (float*)(base);           // 16384 f
    float* sqy    = (float*)(base + 65536);   // 128 f
    float* ed_raw = (float*)(base + 66048);   // 8192 f
    float* edq    = (float*)(base + 98816);   // 64 f
    short* xh = (short*)(base + (1 << 20));   // 16.78M shorts
    short* yh = xh + 16777216;                // 131072 shorts

    hipMemsetAsync(base + 66048, 0, 33024, stream);  // ed_raw + edq

    convert_ssq_kernel<<<(N_ * L_ + M_) / 4, 256, 0, stream>>>(x, y, xh, yh, sqx, sqy);

    ed_mfma_kernel<<<768, 256, 0, stream>>>(xh, yh, sqx, sqy, mask, ed_raw, edq);

    score_kernel<<<1, 256, 0, stream>>>(ed_raw, edq, mask, (float*)d_out);
}